// Round 3
// baseline (56.597 us; speedup 1.0000x reference)
//
#include <hip/hip_runtime.h>
#include <math.h>

// Problem constants (fixed by the reference)
#define H_VAL   7500.0f
#define EH_VAL  750.0f          // 0.1f * 7500.0f, fp32-exact
#define N_DIM   64
#define T_DIM   65536
#define BLOCKS_PER_N 16
#define NBLOCKS (N_DIM * BLOCKS_PER_N)       // 1024
#define THREADS 256
#define T_PER_BLOCK (T_DIM / BLOCKS_PER_N)   // 4096
#define ITERS (T_PER_BLOCK / THREADS)        // 16

__device__ __forceinline__ float dev_nan() { return __uint_as_float(0x7fc00000u); }
__device__ __forceinline__ bool is_nan(float x) { return x != x; }

// Per-(n,c) statistics, 7 values: {sum_all, sum_o, sum_u, sum_e, cnt_o, cnt_u, cnt_e}
// MODE partials (default): ws[block * 28 + c*7 + k], reduced by stage2.
// MODE atomic (fallback if ws too small): ws[n*32 + c*8 + k], memset first.

template <bool ATOMIC>
__global__ __launch_bounds__(THREADS) void mae_stage1(
        const float* __restrict__ outp, const float* __restrict__ tgtp,
        float* __restrict__ ws) {
    const int n = blockIdx.x / BLOCKS_PER_N;
    const int slice = blockIdx.x % BLOCKS_PER_N;
    const int t0 = slice * T_PER_BLOCK;
    const float h = H_VAL;
    const float eh = EH_VAL;

    // 28 live accumulators, w[28..31] = 0 pads for the 32-slot butterfly
    float w[32];
    #pragma unroll
    for (int i = 0; i < 32; ++i) w[i] = 0.0f;

    const float4* o4 = reinterpret_cast<const float4*>(outp) + (size_t)n * T_DIM;
    const float4* t4 = reinterpret_cast<const float4*>(tgtp) + (size_t)n * T_DIM;

    #pragma unroll 4
    for (int it = 0; it < ITERS; ++it) {
        const int t = t0 + it * THREADS + (int)threadIdx.x;
        const float4 ov = o4[t];
        const float4 tv = t4[t];
        const float os[4] = {ov.x, ov.y, ov.z, ov.w};
        const float ts[4] = {tv.x, tv.y, tv.z, tv.w};
        #pragma unroll
        for (int c = 0; c < 4; ++c) {
            const float traw = ts[c];
            // clamp condition AND (tc==h) coincide: (traw>=h)||(traw<0)
            const bool bo = (traw >= h) || (traw < 0.0f);
            const float tc = bo ? h : traw;
            const float d = fabsf(os[c] - tc);
            const bool bu = (traw == 0.0f);
            const bool be = (traw > 0.0f) && (traw < eh);

            w[c * 7 + 0] += d;                    // sum over ALL elements
            w[c * 7 + 1] += bo ? d : 0.0f;        // over-horizon sum
            w[c * 7 + 2] += bu ? d : 0.0f;        // target==0 sum
            w[c * 7 + 3] += be ? d : 0.0f;        // early sum
            w[c * 7 + 4] += bo ? 1.0f : 0.0f;     // counts (<=16, exact)
            w[c * 7 + 5] += bu ? 1.0f : 0.0f;
            w[c * 7 + 6] += be ? 1.0f : 0.0f;
        }
    }

    // Split-butterfly: reduce 32 slots across 64 lanes in 32 shuffles.
    // After round r (dist=2^r), each lane keeps half its slots; final
    // slot owned by lane = 5-bit bit-reversal of (lane & 31).
    const int lane = threadIdx.x & 63;
    #pragma unroll
    for (int r = 0; r < 5; ++r) {
        const int dist = 1 << r;
        const bool hi = (lane >> r) & 1;
        const int cnt = 16 >> r;
        #pragma unroll
        for (int j = 0; j < cnt; ++j) {
            const float send = hi ? w[j] : w[j + cnt];
            const float recv = __shfl_xor(send, dist, 64);
            w[j] = (hi ? w[j + cnt] : w[j]) + recv;
        }
    }
    w[0] += __shfl_xor(w[0], 32, 64);   // merge lane-halves (bit 5 unused by slots)
    const int l5 = lane & 31;
    const int slot = ((l5 & 1) << 4) | (((l5 >> 1) & 1) << 3) | (((l5 >> 2) & 1) << 2) |
                     (((l5 >> 3) & 1) << 1) | ((l5 >> 4) & 1);

    __shared__ float lsum[4][28];
    const int wave = threadIdx.x >> 6;
    if (lane < 32 && slot < 28) lsum[wave][slot] = w[0];
    __syncthreads();

    if (threadIdx.x < 28) {
        const int i = threadIdx.x;
        const float s = lsum[0][i] + lsum[1][i] + lsum[2][i] + lsum[3][i];
        if (ATOMIC) {
            const int c = i / 7, k = i % 7;
            atomicAdd(&ws[n * 32 + c * 8 + k], s);
        } else {
            ws[blockIdx.x * 28 + i] = s;
        }
    }
}

template <bool ATOMIC>
__global__ __launch_bounds__(256) void mae_stage2(
        const float* __restrict__ ws, float* __restrict__ outp) {
    const int i = threadIdx.x;            // 0..255 == (n,c) pair
    const int n = i >> 2, c = i & 3;

    float a[7];
    if (ATOMIC) {
        const float* p = &ws[n * 32 + c * 8];
        #pragma unroll
        for (int k = 0; k < 7; ++k) a[k] = p[k];
    } else {
        #pragma unroll
        for (int k = 0; k < 7; ++k) a[k] = 0.0f;
        for (int s = 0; s < BLOCKS_PER_N; ++s) {
            const float* p = &ws[(n * BLOCKS_PER_N + s) * 28 + c * 7];
            #pragma unroll
            for (int k = 0; k < 7; ++k) a[k] += p[k];
        }
    }

    const float sum_all = a[0], sum_o = a[1], sum_u = a[2], sum_e = a[3];
    const float cnt_o = a[4], cnt_u = a[5], cnt_e = a[6];
    const float cnt_in = (float)T_DIM - cnt_o - cnt_u;   // exact in fp32
    const float sum_in = sum_all - sum_o - sum_u;

    const float m_o  = (cnt_o  > 0.0f) ? sum_o  / cnt_o  : dev_nan();
    const float m_in = (cnt_in > 0.0f) ? sum_in / cnt_in : dev_nan();
    const float m_u  = (cnt_u  > 0.0f) ? sum_u  / cnt_u  : dev_nan();
    const float m_e  = (cnt_e  > 0.0f) ? sum_e  / cnt_e  : dev_nan();

    auto nm2 = [](float x, float y) {
        const bool vx = !is_nan(x), vy = !is_nan(y);
        const float s  = (vx ? x : 0.0f) + (vy ? y : 0.0f);
        const float cc = (vx ? 1.0f : 0.0f) + (vy ? 1.0f : 0.0f);
        return (cc > 0.0f) ? s / cc : dev_nan();
    };
    const float in_comb = nm2(m_u, m_in);
    const float wv      = nm2(m_o, in_comb);

    float vals[4] = {wv, in_comb, m_o, m_e};   // -> wMAE, inMAE, oMAE, eMAE
    float sums[4], cnts[4];
    #pragma unroll
    for (int j = 0; j < 4; ++j) {
        const bool valid = !is_nan(vals[j]);
        sums[j] = valid ? vals[j] : 0.0f;
        cnts[j] = valid ? 1.0f : 0.0f;
    }
    #pragma unroll
    for (int j = 0; j < 4; ++j) {
        #pragma unroll
        for (int off = 32; off > 0; off >>= 1) {
            sums[j] += __shfl_down(sums[j], off, 64);
            cnts[j] += __shfl_down(cnts[j], off, 64);
        }
    }
    __shared__ float ls[4][8];
    const int wave = threadIdx.x >> 6;
    const int lane = threadIdx.x & 63;
    if (lane == 0) {
        #pragma unroll
        for (int j = 0; j < 4; ++j) { ls[wave][j] = sums[j]; ls[wave][j + 4] = cnts[j]; }
    }
    __syncthreads();
    if (threadIdx.x == 0) {
        #pragma unroll
        for (int j = 0; j < 4; ++j) {
            const float s  = ls[0][j] + ls[1][j] + ls[2][j] + ls[3][j];
            const float cc = ls[0][j + 4] + ls[1][j + 4] + ls[2][j + 4] + ls[3][j + 4];
            outp[j] = (cc > 0.0f) ? s / cc : dev_nan();
        }
    }
}

extern "C" void kernel_launch(void* const* d_in, const int* in_sizes, int n_in,
                              void* d_out, int out_size, void* d_ws, size_t ws_size,
                              hipStream_t stream) {
    const float* out_rsd = (const float*)d_in[0];
    const float* tgt_rsd = (const float*)d_in[1];
    float* outv = (float*)d_out;
    float* ws = (float*)d_ws;

    const size_t partials_bytes = (size_t)NBLOCKS * 28 * sizeof(float);
    if (ws_size >= partials_bytes) {
        // No memset, no atomics: every partial slot is written unconditionally.
        mae_stage1<false><<<NBLOCKS, THREADS, 0, stream>>>(out_rsd, tgt_rsd, ws);
        mae_stage2<false><<<1, 256, 0, stream>>>(ws, outv);
    } else {
        // Fallback: 8 KB accumulator + atomics (deterministic; ws_size is fixed).
        hipMemsetAsync(ws, 0, N_DIM * 32 * sizeof(float), stream);
        mae_stage1<true><<<NBLOCKS, THREADS, 0, stream>>>(out_rsd, tgt_rsd, ws);
        mae_stage2<true><<<1, 256, 0, stream>>>(ws, outv);
    }
}

// Round 4
// 32.149 us; speedup vs baseline: 1.7605x; 1.7605x over previous
//
#include <hip/hip_runtime.h>
#include <math.h>

// Problem constants (fixed by the reference)
#define H_VAL   7500.0f
#define EH_VAL  750.0f          // 0.1f * 7500.0f, fp32-exact
#define N_DIM   64
#define T_DIM   65536
#define BLOCKS_PER_N 32
#define NBLOCKS (N_DIM * BLOCKS_PER_N)       // 2048
#define THREADS 256
#define T_PER_BLOCK (T_DIM / BLOCKS_PER_N)   // 2048
#define ITERS (T_PER_BLOCK / THREADS)        // 8

__device__ __forceinline__ float dev_nan() { return __uint_as_float(0x7fc00000u); }
__device__ __forceinline__ bool is_nan(float x) { return x != x; }

// Per-(n,c) statistics, 7 values: {sum_all, sum_o, sum_u, sum_e, cnt_o, cnt_u, cnt_e}
// Partials mode: ws[block*28 + (0..15 sums: c*4+k | 16..27 counts: 16+f*4+c)]
// Atomic fallback: ws[n*32 + c*8 + (0..3 sums | 4..6 counts)], memset first.

template <bool ATOMIC>
__global__ __launch_bounds__(THREADS) void mae_stage1(
        const float* __restrict__ outp, const float* __restrict__ tgtp,
        float* __restrict__ ws) {
    const int n = blockIdx.x / BLOCKS_PER_N;
    const int slice = blockIdx.x % BLOCKS_PER_N;
    const int t0 = slice * T_PER_BLOCK;
    const int tid = threadIdx.x;
    const float h = H_VAL;
    const float eh = EH_VAL;

    // 16 float sums: w[c*4 + {0:all,1:o,2:u,3:e}]
    float w[16];
    #pragma unroll
    for (int i = 0; i < 16; ++i) w[i] = 0.0f;
    // 4 packed u32 counters: bits 0-9 = cnt_o, 10-19 = cnt_u, 20-29 = cnt_e
    unsigned cnt[4] = {0u, 0u, 0u, 0u};

    const float4* o4 = reinterpret_cast<const float4*>(outp) + (size_t)n * T_DIM;
    const float4* t4 = reinterpret_cast<const float4*>(tgtp) + (size_t)n * T_DIM;

    auto proc = [&](const float4& ov, const float4& tv) {
        const float os[4] = {ov.x, ov.y, ov.z, ov.w};
        const float ts[4] = {tv.x, tv.y, tv.z, tv.w};
        #pragma unroll
        for (int c = 0; c < 4; ++c) {
            const float traw = ts[c];
            const bool bo = (traw >= h) || (traw < 0.0f);  // == (tc==h)
            const float tc = bo ? h : traw;
            const float d = fabsf(os[c] - tc);
            const bool bu = (traw == 0.0f);
            const bool be = (traw > 0.0f) && (traw < eh);
            w[c * 4 + 0] += d;
            w[c * 4 + 1] += bo ? d : 0.0f;
            w[c * 4 + 2] += bu ? d : 0.0f;
            w[c * 4 + 3] += be ? d : 0.0f;
            cnt[c] += (bo ? 1u : 0u) + (bu ? (1u << 10) : 0u) + (be ? (1u << 20) : 0u);
        }
    };

#define IDX(i) ((size_t)(t0 + (i) * THREADS + tid))
    // 2-deep software pipeline: 4 float4 loads always in flight.
    float4 a0o = o4[IDX(0)], a1o = o4[IDX(1)];
    float4 a0t = t4[IDX(0)], a1t = t4[IDX(1)];
    #pragma unroll
    for (int it = 0; it < ITERS; it += 2) {
        float4 b0o = a0o, b1o = a1o, b0t = a0t, b1t = a1t;
        if (it + 2 < ITERS) {
            b0o = o4[IDX(it + 2)]; b1o = o4[IDX(it + 3)];
            b0t = t4[IDX(it + 2)]; b1t = t4[IDX(it + 3)];
        }
        proc(a0o, a0t);
        proc(a1o, a1t);
        a0o = b0o; a1o = b1o; a0t = b0t; a1t = b1t;
    }
#undef IDX

    // --- Split-butterfly: 16 sums across 64 lanes in 17 shuffles ---
    const int lane = tid & 63;
    #pragma unroll
    for (int r = 0; r < 4; ++r) {
        const int dist = 1 << r;
        const bool hi = (lane >> r) & 1;
        const int c16 = 8 >> r;
        #pragma unroll
        for (int j = 0; j < c16; ++j) {
            const float send = hi ? w[j] : w[j + c16];
            const float recv = __shfl_xor(send, dist, 64);
            w[j] = (hi ? w[j + c16] : w[j]) + recv;
        }
    }
    w[0] += __shfl_xor(w[0], 16, 64);
    w[0] += __shfl_xor(w[0], 32, 64);
    const int l4 = lane & 15;
    const int slot = ((l4 & 1) << 3) | (((l4 >> 1) & 1) << 2) |
                     (((l4 >> 2) & 1) << 1) | ((l4 >> 3) & 1);

    // --- Packed counts: 4 slots across 64 lanes in 7 shuffles ---
    #pragma unroll
    for (int r = 0; r < 2; ++r) {
        const int dist = 1 << r;
        const bool hi = (lane >> r) & 1;
        const int c4 = 2 >> r;
        #pragma unroll
        for (int j = 0; j < c4; ++j) {
            const unsigned send = hi ? cnt[j] : cnt[j + c4];
            const unsigned recv = __shfl_xor(send, dist, 64);
            cnt[j] = (hi ? cnt[j + c4] : cnt[j]) + recv;
        }
    }
    cnt[0] += __shfl_xor(cnt[0], 4, 64);
    cnt[0] += __shfl_xor(cnt[0], 8, 64);
    cnt[0] += __shfl_xor(cnt[0], 16, 64);
    cnt[0] += __shfl_xor(cnt[0], 32, 64);
    const int slot2 = ((lane & 1) << 1) | ((lane >> 1) & 1);

    __shared__ float    lsum[4][16];
    __shared__ unsigned lcnt[4][4];
    const int wave = tid >> 6;
    if (lane < 16) lsum[wave][slot] = w[0];
    if (lane < 4)  lcnt[wave][slot2] = cnt[0];
    __syncthreads();

    if (tid < 16) {
        const float s = lsum[0][tid] + lsum[1][tid] + lsum[2][tid] + lsum[3][tid];
        if (ATOMIC) {
            const int c = tid >> 2, k = tid & 3;
            atomicAdd(&ws[n * 32 + c * 8 + k], s);
        } else {
            ws[blockIdx.x * 28 + tid] = s;
        }
    } else if (tid < 28) {
        const int j = tid - 16, f = j >> 2, c = j & 3;
        const unsigned v = ((lcnt[0][c] >> (10 * f)) & 1023u) +
                           ((lcnt[1][c] >> (10 * f)) & 1023u) +
                           ((lcnt[2][c] >> (10 * f)) & 1023u) +
                           ((lcnt[3][c] >> (10 * f)) & 1023u);
        const float fv = (float)v;
        if (ATOMIC) {
            atomicAdd(&ws[n * 32 + c * 8 + 4 + f], fv);
        } else {
            ws[blockIdx.x * 28 + tid] = fv;
        }
    }
}

template <bool ATOMIC>
__global__ __launch_bounds__(256) void mae_stage2(
        const float* __restrict__ ws, float* __restrict__ outp) {
    const int i = threadIdx.x;            // 0..255 == (n,c) pair
    const int n = i >> 2, c = i & 3;

    float a[7];
    if (ATOMIC) {
        const float* p = &ws[n * 32 + c * 8];
        #pragma unroll
        for (int k = 0; k < 4; ++k) a[k] = p[k];
        #pragma unroll
        for (int f = 0; f < 3; ++f) a[4 + f] = p[4 + f];
    } else {
        #pragma unroll
        for (int k = 0; k < 7; ++k) a[k] = 0.0f;
        for (int s = 0; s < BLOCKS_PER_N; ++s) {
            const float* p = &ws[(size_t)(n * BLOCKS_PER_N + s) * 28];
            #pragma unroll
            for (int k = 0; k < 4; ++k) a[k] += p[c * 4 + k];
            #pragma unroll
            for (int f = 0; f < 3; ++f) a[4 + f] += p[16 + f * 4 + c];
        }
    }

    const float sum_all = a[0], sum_o = a[1], sum_u = a[2], sum_e = a[3];
    const float cnt_o = a[4], cnt_u = a[5], cnt_e = a[6];
    const float cnt_in = (float)T_DIM - cnt_o - cnt_u;   // exact in fp32
    const float sum_in = sum_all - sum_o - sum_u;

    const float m_o  = (cnt_o  > 0.0f) ? sum_o  / cnt_o  : dev_nan();
    const float m_in = (cnt_in > 0.0f) ? sum_in / cnt_in : dev_nan();
    const float m_u  = (cnt_u  > 0.0f) ? sum_u  / cnt_u  : dev_nan();
    const float m_e  = (cnt_e  > 0.0f) ? sum_e  / cnt_e  : dev_nan();

    auto nm2 = [](float x, float y) {
        const bool vx = !is_nan(x), vy = !is_nan(y);
        const float s  = (vx ? x : 0.0f) + (vy ? y : 0.0f);
        const float cc = (vx ? 1.0f : 0.0f) + (vy ? 1.0f : 0.0f);
        return (cc > 0.0f) ? s / cc : dev_nan();
    };
    const float in_comb = nm2(m_u, m_in);
    const float wv      = nm2(m_o, in_comb);

    float vals[4] = {wv, in_comb, m_o, m_e};   // -> wMAE, inMAE, oMAE, eMAE
    float sums[4], cnts[4];
    #pragma unroll
    for (int j = 0; j < 4; ++j) {
        const bool valid = !is_nan(vals[j]);
        sums[j] = valid ? vals[j] : 0.0f;
        cnts[j] = valid ? 1.0f : 0.0f;
    }
    #pragma unroll
    for (int j = 0; j < 4; ++j) {
        #pragma unroll
        for (int off = 32; off > 0; off >>= 1) {
            sums[j] += __shfl_down(sums[j], off, 64);
            cnts[j] += __shfl_down(cnts[j], off, 64);
        }
    }
    __shared__ float ls[4][8];
    const int wave = threadIdx.x >> 6;
    const int lane = threadIdx.x & 63;
    if (lane == 0) {
        #pragma unroll
        for (int j = 0; j < 4; ++j) { ls[wave][j] = sums[j]; ls[wave][j + 4] = cnts[j]; }
    }
    __syncthreads();
    if (threadIdx.x == 0) {
        #pragma unroll
        for (int j = 0; j < 4; ++j) {
            const float s  = ls[0][j] + ls[1][j] + ls[2][j] + ls[3][j];
            const float cc = ls[0][j + 4] + ls[1][j + 4] + ls[2][j + 4] + ls[3][j + 4];
            outp[j] = (cc > 0.0f) ? s / cc : dev_nan();
        }
    }
}

extern "C" void kernel_launch(void* const* d_in, const int* in_sizes, int n_in,
                              void* d_out, int out_size, void* d_ws, size_t ws_size,
                              hipStream_t stream) {
    const float* out_rsd = (const float*)d_in[0];
    const float* tgt_rsd = (const float*)d_in[1];
    float* outv = (float*)d_out;
    float* ws = (float*)d_ws;

    const size_t partials_bytes = (size_t)NBLOCKS * 28 * sizeof(float);
    if (ws_size >= partials_bytes) {
        // No memset, no atomics: every partial slot is written unconditionally.
        mae_stage1<false><<<NBLOCKS, THREADS, 0, stream>>>(out_rsd, tgt_rsd, ws);
        mae_stage2<false><<<1, 256, 0, stream>>>(ws, outv);
    } else {
        // Fallback: 8 KB accumulator + atomics (deterministic; ws_size is fixed).
        hipMemsetAsync(ws, 0, N_DIM * 32 * sizeof(float), stream);
        mae_stage1<true><<<NBLOCKS, THREADS, 0, stream>>>(out_rsd, tgt_rsd, ws);
        mae_stage2<true><<<1, 256, 0, stream>>>(ws, outv);
    }
}